// Round 3
// baseline (137.677 us; speedup 1.0000x reference)
//
#include <hip/hip_runtime.h>
#include <math.h>

#define BB 64
#define NN 64
#define NM1 63
#define RR (NN*(NN-1))

typedef short bf16x8 __attribute__((ext_vector_type(8)));
typedef float f32x4 __attribute__((ext_vector_type(4)));
union U4 { uint4 u; bf16x8 b; };

__device__ inline unsigned int f2bf(float f) {
    unsigned int u = __float_as_uint(f);
    return (u + 0x7FFFu + ((u >> 16) & 1u)) >> 16;   // RNE fp32->bf16
}
__device__ inline unsigned int pack2(float a, float b) {
    return f2bf(a) | (f2bf(b) << 16);
}

// ============ single fused kernel: G=8 receivers/block, 512 threads ========
// Weights read f32 from global (L2-resident) and packed to bf16 in-register,
// software-pipelined so every global wait is covered by MFMA/store work.
// LDS conflict fixes: relb_w 16B-chunk XOR swizzle (A-frag reads were 8-way),
// P padded to stride 29 (phase-1 reads were 8-way).
// __launch_bounds__(512,4): VGPR<=128, 2 blocks/CU (LDS ~55.8KB).
__global__ __launch_bounds__(512, 4) void fused_kernel(
    const float* __restrict__ objects_state,
    const float* __restrict__ objects_shape,
    const float* __restrict__ relation_info,
    const float* __restrict__ s_mean, const float* __restrict__ s_std,
    const float* __restrict__ sh_mean, const float* __restrict__ sh_std,
    const float* __restrict__ v_mean, const float* __restrict__ v_std,
    const float* __restrict__ W1, const float* __restrict__ b1,
    const float* __restrict__ W2, const float* __restrict__ b2,
    const float* __restrict__ W3, const float* __restrict__ b3,
    const float* __restrict__ W4, const float* __restrict__ b4,
    float* __restrict__ out)
{
    __shared__ __align__(16) float P[64][29];                 // 7424 B (29: bank-coprime)
    __shared__ __align__(16) unsigned int relb_w[8*64*16];    // 32768 B
    __shared__ __align__(16) unsigned short s_h[16*264];      // 8448 B
    __shared__ __align__(16) unsigned short s_q[16*168];      // 5376 B
    __shared__ int   s_cntg[8];
    __shared__ float s_red[8][16][3];
    __shared__ float s_outv[16][3];

    const int b  = blockIdx.x >> 3;
    const int nb = (blockIdx.x & 7) * 8;
    const int t  = threadIdx.x;
    const int wv = t >> 6, lane = t & 63, col16 = lane & 15, quad = lane >> 4;

    // ---- W1 B-frag f32 loads (compact-row mapping), issued first so the
    // L2/HBM latency hides under phase 0. Converted after the first barrier.
    float w1v[16], b10, b11;
    {
        const int cA = wv*32 + col16, cB = cA + 16;
        #pragma unroll
        for (int j = 0; j < 8; ++j) {
            const int k = quad*8 + j;
            // kc<12 -> orig kc; 12..21 -> +10 (sender shape); 22..31 -> -10
            const int orig = k < 12 ? k : (k < 22 ? k+10 : k-10);
            w1v[j]   = W1[orig*256 + cA];
            w1v[8+j] = W1[orig*256 + cB];
        }
        b10 = b1[cA]; b11 = b1[cB];
    }

    // ---- relation_info direct per-thread read: 12B each, pre-barrier ----
    float ri0 = 0.f, ri1 = 0.f, ri2 = 0.f;
    if (t < 504) {
        const float* rp = relation_info + ((size_t)b*RR + nb*NM1 + t)*3;
        ri0 = rp[0]; ri1 = rp[1]; ri2 = rp[2];
    }

    // ---- epilogue scalar prefetch ----
    float e_vs0=0.f,e_vs1=0.f,e_vs2=0.f,e_vm0=0.f,e_vm1=0.f,e_vm2=0.f,e_b4=0.f;
    if (t < 48) {
        e_vs0 = v_std[0]; e_vs1 = v_std[1]; e_vs2 = v_std[2];
        e_vm0 = v_mean[0]; e_vm1 = v_mean[1]; e_vm2 = v_mean[2];
        e_b4  = b4[t % 3];
    }

    // ---- Phase 0: zero-init + per-object record compute ----
    // Per-object record (29 f32): [0]=st0 [1]=st1 [2..9]=nst [10..19]=nsh
    // [20]=cos(nst2) [21]=sin(nst2) [22]=cos(st2) [23]=sin(st2)
    // [24]=vrot0 [25]=vrot1 [26]=st2raw [27..28]=pad
    {
        uint4 z = make_uint4(0,0,0,0);
        uint4* relb4 = (uint4*)relb_w;
        #pragma unroll
        for (int r = 0; r < 4; ++r) relb4[r*512 + t] = z;
        if (t < 336) ((uint4*)s_q)[t] = z;
        if (t < 8) s_cntg[t] = 0;
        if (t < 64) {
            const int n = b*64 + t;
            const float4* sp4 = (const float4*)(objects_state + (size_t)n*8);
            const float4 sA = sp4[0], sB = sp4[1];
            float st[8] = {sA.x, sA.y, sA.z, sA.w, sB.x, sB.y, sB.z, sB.w};
            const float2* hp2 = (const float2*)(objects_shape + (size_t)n*10);
            float sh[10];
            #pragma unroll
            for (int c = 0; c < 5; ++c) {
                const float2 v = hp2[c];
                sh[c*2] = v.x; sh[c*2+1] = v.y;
            }
            float f[28];
            f[0] = st[0]; f[1] = st[1]; f[26] = st[2]; f[27] = 0.f;
            #pragma unroll
            for (int c = 0; c < 8; ++c)  f[2+c]  = (st[c] - s_mean[c]) / s_std[c];
            #pragma unroll
            for (int c = 0; c < 10; ++c) f[10+c] = (sh[c] - sh_mean[c]) / sh_std[c];
            // libm sinf/cosf to match reference precision
            const float sa = sinf(f[4]), ca = cosf(f[4]);
            const float sr = sinf(st[2]), cr = cosf(st[2]);
            f[20] = ca; f[21] = sa; f[22] = cr; f[23] = sr;
            f[24] =  ca*f[5] + sa*f[6];
            f[25] = -sa*f[5] + ca*f[6];
            #pragma unroll
            for (int c = 0; c < 28; ++c) P[t][c] = f[c];
        }
    }
    __syncthreads();

    // convert W1 frags (loads complete by now)
    U4 bu0, bu1;
    bu0.u.x = pack2(w1v[0],  w1v[1]);  bu0.u.y = pack2(w1v[2],  w1v[3]);
    bu0.u.z = pack2(w1v[4],  w1v[5]);  bu0.u.w = pack2(w1v[6],  w1v[7]);
    bu1.u.x = pack2(w1v[8],  w1v[9]);  bu1.u.y = pack2(w1v[10], w1v[11]);
    bu1.u.z = pack2(w1v[12], w1v[13]); bu1.u.w = pack2(w1v[14], w1v[15]);

    // ---- Phase 1: build relation rows (1 candidate/thread) ----
    // relb_w layout: row = 64B = 4x16B chunks, chunk swizzled by
    // chunk' = chunk ^ ((row>>1)&3) -> A-frag reads & these writes are ~2-way.
    if (t < 504) {
        const int g = t/63, k = t - g*63, n = nb + g, j = k + (k >= n);
        const float dx = P[n][0] - P[j][0];
        const float dy = P[n][1] - P[j][1];
        const float dist = sqrtf(dx*dx + dy*dy);
        if (dist < 0.35f && dist != 0.0f) {
            const int slot = atomicAdd(&s_cntg[g], 1);
            const int row = (g << 6) + slot;
            const int sw = (row >> 1) & 3;
            uint4* dst = (uint4*)&relb_w[row*16];
            const float ca = P[n][20], sa = P[n][21];
            const float d0 = P[j][2]-P[n][2], d1 = P[j][3]-P[n][3];
            const float d2 = P[j][4]-P[n][4], d3 = P[j][5]-P[n][5];
            const float d4 = P[j][6]-P[n][6], d5 = P[j][7]-P[n][7];
            uint4 o;
            o.x = pack2(ri0, ri1);
            o.y = pack2(ri2, ca*d0 + sa*d1);
            o.z = pack2(-sa*d0 + ca*d1, ca*d3 + sa*d4);
            o.w = pack2(-sa*d3 + ca*d4, ca*P[j][8] + sa*P[j][9]);
            dst[0 ^ sw] = o;
            o.x = pack2(-sa*P[j][8] + ca*P[j][9], sinf(2.f*d2));
            o.y = pack2(cosf(2.f*d2), d5);
            o.z = pack2(P[j][10], P[j][11]);
            o.w = pack2(P[j][12], P[j][13]);
            dst[1 ^ sw] = o;
            o.x = pack2(P[j][14], P[j][15]);
            o.y = pack2(P[j][16], P[j][17]);
            o.z = pack2(P[j][18], P[j][19]);
            o.w = pack2(P[n][10], P[n][11]);
            dst[2 ^ sw] = o;
            o.x = pack2(P[n][12], P[n][13]);
            o.y = pack2(P[n][14], P[n][15]);
            o.z = pack2(P[n][16], P[n][17]);
            o.w = pack2(P[n][18], P[n][19]);
            dst[3 ^ sw] = o;
        }
    }
    __syncthreads();

    // per-thread read swizzle for A-frags: row low bits = col16
    const int rd_sw = (quad ^ ((col16 >> 1) & 3)) * 4;

    // ---- Phase 2: MLP1 MFMA (per wave: 2 N-tiles over 8 groups) ----
    U4 w2f[8];
    float b2v;
    {
        int cg[8];
        #pragma unroll
        for (int g = 0; g < 8; ++g) cg[g] = s_cntg[g];
        float hs0[8], hs1[8];
        #pragma unroll
        for (int g = 0; g < 8; ++g) { hs0[g] = 0.f; hs1[g] = 0.f; }
        #pragma unroll
        for (int g = 0; g < 8; ++g) {
            const int mts = (cg[g] + 15) >> 4;
            for (int mt = 0; mt < mts; ++mt) {
                U4 au;
                au.u = *(const uint4*)&relb_w[((g<<6) + mt*16 + col16)*16 + rd_sw];
                f32x4 a0 = {0.f,0.f,0.f,0.f}, a1 = {0.f,0.f,0.f,0.f};
                a0 = __builtin_amdgcn_mfma_f32_16x16x32_bf16(au.b, bu0.b, a0, 0,0,0);
                a1 = __builtin_amdgcn_mfma_f32_16x16x32_bf16(au.b, bu1.b, a1, 0,0,0);
                #pragma unroll
                for (int i = 0; i < 4; ++i) {
                    hs0[g] += fmaxf(a0[i] + b10, 0.f);
                    hs1[g] += fmaxf(a1[i] + b11, 0.f);
                }
            }
        }
        // issue first half of W2 (hides under the reduction below)
        float w2rA[32];
        #pragma unroll
        for (int kc = 0; kc < 4; ++kc)
            #pragma unroll
            for (int j = 0; j < 8; ++j)
                w2rA[kc*8+j] = W2[(size_t)(kc*32 + quad*8 + j)*128 + wv*16 + col16];
        b2v = b2[wv*16 + col16];
        // zero pad rows each contributed relu(b1); subtract post-hoc
        const float rb0 = fmaxf(b10, 0.f), rb1 = fmaxf(b11, 0.f);
        #pragma unroll
        for (int g = 0; g < 8; ++g) {
            const int mts = (cg[g] + 15) >> 4;
            const float pad = (float)(mts*16 - cg[g]);
            float v0 = hs0[g], v1 = hs1[g];
            v0 += __shfl_xor(v0, 16); v0 += __shfl_xor(v0, 32);
            v1 += __shfl_xor(v1, 16); v1 += __shfl_xor(v1, 32);
            if (quad == 0) {
                s_h[g*264 + (wv*2+0)*16 + col16] =
                    (unsigned short)f2bf(v0 - pad*rb0);
                s_h[g*264 + (wv*2+1)*16 + col16] =
                    (unsigned short)f2bf(v1 - pad*rb1);
            }
        }
        // second half of W2 + pack both halves
        float w2rB[32];
        #pragma unroll
        for (int kc = 0; kc < 4; ++kc)
            #pragma unroll
            for (int j = 0; j < 8; ++j)
                w2rB[kc*8+j] = W2[(size_t)((kc+4)*32 + quad*8 + j)*128 + wv*16 + col16];
        #pragma unroll
        for (int kc = 0; kc < 4; ++kc) {
            U4 o;
            o.u.x = pack2(w2rA[kc*8+0], w2rA[kc*8+1]);
            o.u.y = pack2(w2rA[kc*8+2], w2rA[kc*8+3]);
            o.u.z = pack2(w2rA[kc*8+4], w2rA[kc*8+5]);
            o.u.w = pack2(w2rA[kc*8+6], w2rA[kc*8+7]);
            w2f[kc] = o;
        }
        #pragma unroll
        for (int kc = 0; kc < 4; ++kc) {
            U4 o;
            o.u.x = pack2(w2rB[kc*8+0], w2rB[kc*8+1]);
            o.u.y = pack2(w2rB[kc*8+2], w2rB[kc*8+3]);
            o.u.z = pack2(w2rB[kc*8+4], w2rB[kc*8+5]);
            o.u.w = pack2(w2rB[kc*8+6], w2rB[kc*8+7]);
            w2f[4+kc] = o;
        }
    }
    __syncthreads();

    // ---- Phase 3: obj_data q[0..12] + W2 GEMM -> q[13..140] ----
    U4 w3f0[5];
    float b3p0, w4p0[3];
    if (t < 104) {
        const int m = t/13, c = t - m*13, n = nb + m;
        float v;
        if (c == 0) v = P[n][24];
        else if (c == 1) v = P[n][25];
        else if (c == 2) v = P[n][7];
        else v = P[n][10 + c - 3];
        s_q[m*168 + c] = (unsigned short)f2bf(v);
    }
    {
        U4 af[8];
        #pragma unroll
        for (int kc = 0; kc < 8; ++kc)
            af[kc].u = *(const uint4*)&s_h[(lane & 15)*264 + kc*32 + quad*8];
        float cntv[4];
        #pragma unroll
        for (int i = 0; i < 4; ++i)
            cntv[i] = (float)s_cntg[(quad*4 + i) & 7];
        // issue W3 ntl0 raw loads: hidden under the 8 MFMAs + stores below
        float w3r0[40];
        {
            const int col = wv*16 + col16;
            b3p0 = b3[col];
            w4p0[0] = W4[col*3+0]; w4p0[1] = W4[col*3+1]; w4p0[2] = W4[col*3+2];
            #pragma unroll
            for (int kc = 0; kc < 5; ++kc)
                #pragma unroll
                for (int j = 0; j < 8; ++j) {
                    const int k = kc*32 + quad*8 + j;
                    w3r0[kc*8+j] = (k < 141) ? W3[(size_t)k*256 + col] : 0.f;
                }
        }
        f32x4 acc = {0.f,0.f,0.f,0.f};
        #pragma unroll
        for (int kc = 0; kc < 8; ++kc)
            acc = __builtin_amdgcn_mfma_f32_16x16x32_bf16(af[kc].b, w2f[kc].b, acc, 0,0,0);
        #pragma unroll
        for (int i = 0; i < 4; ++i) {
            const int row = quad*4 + i;
            s_q[row*168 + 13 + wv*16 + col16] =
                (unsigned short)f2bf(acc[i] + cntv[i]*b2v);
        }
        // pack ntl0
        #pragma unroll
        for (int kc = 0; kc < 5; ++kc) {
            U4 o;
            o.u.x = pack2(w3r0[kc*8+0], w3r0[kc*8+1]);
            o.u.y = pack2(w3r0[kc*8+2], w3r0[kc*8+3]);
            o.u.z = pack2(w3r0[kc*8+4], w3r0[kc*8+5]);
            o.u.w = pack2(w3r0[kc*8+6], w3r0[kc*8+7]);
            w3f0[kc] = o;
        }
    }
    __syncthreads();

    // ---- Phase 4: W3 GEMM + relu + W4 partials (ntl1 loads pipelined) ----
    {
        U4 af3[5];
        #pragma unroll
        for (int kc = 0; kc < 5; ++kc)
            af3[kc].u = *(const uint4*)&s_q[(lane & 15)*168 + kc*32 + quad*8];
        // issue ntl1 raw loads; wait covered by ntl0 GEMM below
        float w3r1[40], b3p1, w4p1[3];
        {
            const int col = (wv + 8)*16 + col16;
            b3p1 = b3[col];
            w4p1[0] = W4[col*3+0]; w4p1[1] = W4[col*3+1]; w4p1[2] = W4[col*3+2];
            #pragma unroll
            for (int kc = 0; kc < 5; ++kc)
                #pragma unroll
                for (int j = 0; j < 8; ++j) {
                    const int k = kc*32 + quad*8 + j;
                    w3r1[kc*8+j] = (k < 141) ? W3[(size_t)k*256 + col] : 0.f;
                }
        }
        float p[4][3];
        #pragma unroll
        for (int i = 0; i < 4; ++i) { p[i][0]=0.f; p[i][1]=0.f; p[i][2]=0.f; }
        // ntl0 compute
        {
            f32x4 acc = {0.f,0.f,0.f,0.f};
            #pragma unroll
            for (int kc = 0; kc < 5; ++kc)
                acc = __builtin_amdgcn_mfma_f32_16x16x32_bf16(
                    af3[kc].b, w3f0[kc].b, acc, 0,0,0);
            #pragma unroll
            for (int i = 0; i < 4; ++i) {
                const float h = fmaxf(acc[i] + b3p0, 0.f);
                p[i][0] = fmaf(h, w4p0[0], p[i][0]);
                p[i][1] = fmaf(h, w4p0[1], p[i][1]);
                p[i][2] = fmaf(h, w4p0[2], p[i][2]);
            }
        }
        // pack + compute ntl1
        {
            U4 w3f1[5];
            #pragma unroll
            for (int kc = 0; kc < 5; ++kc) {
                U4 o;
                o.u.x = pack2(w3r1[kc*8+0], w3r1[kc*8+1]);
                o.u.y = pack2(w3r1[kc*8+2], w3r1[kc*8+3]);
                o.u.z = pack2(w3r1[kc*8+4], w3r1[kc*8+5]);
                o.u.w = pack2(w3r1[kc*8+6], w3r1[kc*8+7]);
                w3f1[kc] = o;
            }
            f32x4 acc = {0.f,0.f,0.f,0.f};
            #pragma unroll
            for (int kc = 0; kc < 5; ++kc)
                acc = __builtin_amdgcn_mfma_f32_16x16x32_bf16(
                    af3[kc].b, w3f1[kc].b, acc, 0,0,0);
            #pragma unroll
            for (int i = 0; i < 4; ++i) {
                const float h = fmaxf(acc[i] + b3p1, 0.f);
                p[i][0] = fmaf(h, w4p1[0], p[i][0]);
                p[i][1] = fmaf(h, w4p1[1], p[i][1]);
                p[i][2] = fmaf(h, w4p1[2], p[i][2]);
            }
        }
        #pragma unroll
        for (int off = 1; off < 16; off <<= 1)
            #pragma unroll
            for (int i = 0; i < 4; ++i) {
                p[i][0] += __shfl_xor(p[i][0], off);
                p[i][1] += __shfl_xor(p[i][1], off);
                p[i][2] += __shfl_xor(p[i][2], off);
            }
        if (col16 == 0)
            #pragma unroll
            for (int i = 0; i < 4; ++i) {
                s_red[wv][quad*4+i][0] = p[i][0];
                s_red[wv][quad*4+i][1] = p[i][1];
                s_red[wv][quad*4+i][2] = p[i][2];
            }
    }
    __syncthreads();
    if (t < 48) {
        const int m = t/3, o = t - m*3;
        float acc = e_b4;   // b4[o] prefetched (o == t%3)
        #pragma unroll
        for (int w = 0; w < 8; ++w) acc += s_red[w][m][o];
        s_outv[m][o] = acc;
    }
    __syncthreads();

    // ---- Phase 5: epilogue (all scalars prefetched in phase 0) ----
    if (t < 48) {
        const int m = t/6, i = t - m*6, n = nb + m;
        if (n >= 1) {
            const float q0 = s_outv[m][0]*e_vs0 + e_vm0;
            const float q1 = s_outv[m][1]*e_vs1 + e_vm1;
            const float q2 = s_outv[m][2]*e_vs2 + e_vm2;
            const float cr = P[n][22], sr = P[n][23];
            const float xd0 = cr*q0 - sr*q1;
            const float xd1 = sr*q0 + cr*q1;
            const int im = i % 3;
            const float xd = (im == 0) ? xd0 : (im == 1) ? xd1 : q2;
            float base = 0.f;
            if (i == 0) base = P[n][0];
            else if (i == 1) base = P[n][1];
            else if (i == 2) base = P[n][26];
            out[((size_t)b*NM1 + (n-1))*6 + i] = base + xd;
        }
    }
}

extern "C" void kernel_launch(void* const* d_in, const int* in_sizes, int n_in,
                              void* d_out, int out_size, void* d_ws, size_t ws_size,
                              hipStream_t stream) {
    const float* objects_state = (const float*)d_in[0];
    const float* objects_shape = (const float*)d_in[1];
    const float* relation_info = (const float*)d_in[2];
    const float* s_mean  = (const float*)d_in[3];
    const float* s_std   = (const float*)d_in[4];
    const float* sh_mean = (const float*)d_in[5];
    const float* sh_std  = (const float*)d_in[6];
    const float* v_mean  = (const float*)d_in[7];
    const float* v_std   = (const float*)d_in[8];
    const float* W1 = (const float*)d_in[9];
    const float* b1 = (const float*)d_in[10];
    const float* W2 = (const float*)d_in[11];
    const float* b2 = (const float*)d_in[12];
    const float* W3 = (const float*)d_in[13];
    const float* b3 = (const float*)d_in[14];
    const float* W4 = (const float*)d_in[15];
    const float* b4 = (const float*)d_in[16];
    (void)d_ws; (void)ws_size; (void)in_sizes; (void)n_in; (void)out_size;

    fused_kernel<<<dim3(BB*8), dim3(512), 0, stream>>>(
        objects_state, objects_shape, relation_info,
        s_mean, s_std, sh_mean, sh_std, v_mean, v_std,
        W1, b1, W2, b2, W3, b3, W4, b4,
        (float*)d_out);
}

// Round 4
// 123.723 us; speedup vs baseline: 1.1128x; 1.1128x over previous
//
#include <hip/hip_runtime.h>
#include <math.h>

#define BB 64
#define NN 64
#define NM1 63
#define RR (NN*(NN-1))

typedef short bf16x8 __attribute__((ext_vector_type(8)));
typedef float f32x4 __attribute__((ext_vector_type(4)));
union U4 { uint4 u; bf16x8 b; };

__device__ inline unsigned int f2bf(float f) {
    unsigned int u = __float_as_uint(f);
    return (u + 0x7FFFu + ((u >> 16) & 1u)) >> 16;   // RNE fp32->bf16
}
__device__ inline unsigned int pack2(float a, float b) {
    return f2bf(a) | (f2bf(b) << 16);
}

// ============ single fused kernel: G=8 receivers/block, 512 threads ========
// Weights read f32 from global (L2-resident) and packed to bf16 in-register,
// software-pipelined so global waits are covered by MFMA/store work.
// LDS conflict fixes: relb_w 16B-chunk XOR swizzle, P stride 29.
// amdgpu_waves_per_eu(4,4): pin allocator to 4 waves/EU => 128-VGPR budget.
// (launch_bounds(512,4) alone let it target 8 waves/EU = 64 VGPR -> 82MB of
// scratch spills, measured round 3.)
__global__ __launch_bounds__(512)
__attribute__((amdgpu_waves_per_eu(4, 4)))
void fused_kernel(
    const float* __restrict__ objects_state,
    const float* __restrict__ objects_shape,
    const float* __restrict__ relation_info,
    const float* __restrict__ s_mean, const float* __restrict__ s_std,
    const float* __restrict__ sh_mean, const float* __restrict__ sh_std,
    const float* __restrict__ v_mean, const float* __restrict__ v_std,
    const float* __restrict__ W1, const float* __restrict__ b1,
    const float* __restrict__ W2, const float* __restrict__ b2,
    const float* __restrict__ W3, const float* __restrict__ b3,
    const float* __restrict__ W4, const float* __restrict__ b4,
    float* __restrict__ out)
{
    __shared__ __align__(16) float P[64][29];                 // 7424 B (29: bank-coprime)
    __shared__ __align__(16) unsigned int relb_w[8*64*16];    // 32768 B
    __shared__ __align__(16) unsigned short s_h[16*264];      // 8448 B
    __shared__ __align__(16) unsigned short s_q[16*168];      // 5376 B
    __shared__ int   s_cntg[8];
    __shared__ float s_red[8][16][3];
    __shared__ float s_outv[16][3];

    const int b  = blockIdx.x >> 3;
    const int nb = (blockIdx.x & 7) * 8;
    const int t  = threadIdx.x;
    const int wv = t >> 6, lane = t & 63, col16 = lane & 15, quad = lane >> 4;

    // ---- W1 B-frag f32 loads (compact-row mapping), issued first so the
    // L2/HBM latency hides under phase 0. Converted after the first barrier.
    float w1v[16], b10, b11;
    {
        const int cA = wv*32 + col16, cB = cA + 16;
        #pragma unroll
        for (int j = 0; j < 8; ++j) {
            const int k = quad*8 + j;
            // kc<12 -> orig kc; 12..21 -> +10 (sender shape); 22..31 -> -10
            const int orig = k < 12 ? k : (k < 22 ? k+10 : k-10);
            w1v[j]   = W1[orig*256 + cA];
            w1v[8+j] = W1[orig*256 + cB];
        }
        b10 = b1[cA]; b11 = b1[cB];
    }

    // ---- relation_info direct per-thread read: 12B each, pre-barrier ----
    float ri0 = 0.f, ri1 = 0.f, ri2 = 0.f;
    if (t < 504) {
        const float* rp = relation_info + ((size_t)b*RR + nb*NM1 + t)*3;
        ri0 = rp[0]; ri1 = rp[1]; ri2 = rp[2];
    }

    // ---- epilogue scalar prefetch ----
    float e_vs0=0.f,e_vs1=0.f,e_vs2=0.f,e_vm0=0.f,e_vm1=0.f,e_vm2=0.f,e_b4=0.f;
    if (t < 48) {
        e_vs0 = v_std[0]; e_vs1 = v_std[1]; e_vs2 = v_std[2];
        e_vm0 = v_mean[0]; e_vm1 = v_mean[1]; e_vm2 = v_mean[2];
        e_b4  = b4[t % 3];
    }

    // ---- Phase 0: zero-init + per-object record compute ----
    // Per-object record: [0]=st0 [1]=st1 [2..9]=nst [10..19]=nsh
    // [20]=cos(nst2) [21]=sin(nst2) [22]=cos(st2) [23]=sin(st2)
    // [24]=vrot0 [25]=vrot1 [26]=st2raw [27..28]=pad
    {
        uint4 z = make_uint4(0,0,0,0);
        uint4* relb4 = (uint4*)relb_w;
        #pragma unroll
        for (int r = 0; r < 4; ++r) relb4[r*512 + t] = z;
        if (t < 336) ((uint4*)s_q)[t] = z;
        if (t < 8) s_cntg[t] = 0;
        if (t < 64) {
            const int n = b*64 + t;
            const float4* sp4 = (const float4*)(objects_state + (size_t)n*8);
            const float4 sA = sp4[0], sB = sp4[1];
            float st[8] = {sA.x, sA.y, sA.z, sA.w, sB.x, sB.y, sB.z, sB.w};
            const float2* hp2 = (const float2*)(objects_shape + (size_t)n*10);
            float sh[10];
            #pragma unroll
            for (int c = 0; c < 5; ++c) {
                const float2 v = hp2[c];
                sh[c*2] = v.x; sh[c*2+1] = v.y;
            }
            float f[28];
            f[0] = st[0]; f[1] = st[1]; f[26] = st[2]; f[27] = 0.f;
            #pragma unroll
            for (int c = 0; c < 8; ++c)  f[2+c]  = (st[c] - s_mean[c]) / s_std[c];
            #pragma unroll
            for (int c = 0; c < 10; ++c) f[10+c] = (sh[c] - sh_mean[c]) / sh_std[c];
            // libm sinf/cosf to match reference precision
            const float sa = sinf(f[4]), ca = cosf(f[4]);
            const float sr = sinf(st[2]), cr = cosf(st[2]);
            f[20] = ca; f[21] = sa; f[22] = cr; f[23] = sr;
            f[24] =  ca*f[5] + sa*f[6];
            f[25] = -sa*f[5] + ca*f[6];
            #pragma unroll
            for (int c = 0; c < 28; ++c) P[t][c] = f[c];
        }
    }
    __syncthreads();

    // convert W1 frags (loads complete by now)
    U4 bu0, bu1;
    bu0.u.x = pack2(w1v[0],  w1v[1]);  bu0.u.y = pack2(w1v[2],  w1v[3]);
    bu0.u.z = pack2(w1v[4],  w1v[5]);  bu0.u.w = pack2(w1v[6],  w1v[7]);
    bu1.u.x = pack2(w1v[8],  w1v[9]);  bu1.u.y = pack2(w1v[10], w1v[11]);
    bu1.u.z = pack2(w1v[12], w1v[13]); bu1.u.w = pack2(w1v[14], w1v[15]);

    // ---- Phase 1: build relation rows (1 candidate/thread) ----
    // relb_w layout: row = 64B = 4x16B chunks, chunk' = chunk ^ ((row>>1)&3)
    if (t < 504) {
        const int g = t/63, k = t - g*63, n = nb + g, j = k + (k >= n);
        const float dx = P[n][0] - P[j][0];
        const float dy = P[n][1] - P[j][1];
        const float dist = sqrtf(dx*dx + dy*dy);
        if (dist < 0.35f && dist != 0.0f) {
            const int slot = atomicAdd(&s_cntg[g], 1);
            const int row = (g << 6) + slot;
            const int sw = (row >> 1) & 3;
            uint4* dst = (uint4*)&relb_w[row*16];
            const float ca = P[n][20], sa = P[n][21];
            const float d0 = P[j][2]-P[n][2], d1 = P[j][3]-P[n][3];
            const float d2 = P[j][4]-P[n][4], d3 = P[j][5]-P[n][5];
            const float d4 = P[j][6]-P[n][6], d5 = P[j][7]-P[n][7];
            uint4 o;
            o.x = pack2(ri0, ri1);
            o.y = pack2(ri2, ca*d0 + sa*d1);
            o.z = pack2(-sa*d0 + ca*d1, ca*d3 + sa*d4);
            o.w = pack2(-sa*d3 + ca*d4, ca*P[j][8] + sa*P[j][9]);
            dst[0 ^ sw] = o;
            o.x = pack2(-sa*P[j][8] + ca*P[j][9], sinf(2.f*d2));
            o.y = pack2(cosf(2.f*d2), d5);
            o.z = pack2(P[j][10], P[j][11]);
            o.w = pack2(P[j][12], P[j][13]);
            dst[1 ^ sw] = o;
            o.x = pack2(P[j][14], P[j][15]);
            o.y = pack2(P[j][16], P[j][17]);
            o.z = pack2(P[j][18], P[j][19]);
            o.w = pack2(P[n][10], P[n][11]);
            dst[2 ^ sw] = o;
            o.x = pack2(P[n][12], P[n][13]);
            o.y = pack2(P[n][14], P[n][15]);
            o.z = pack2(P[n][16], P[n][17]);
            o.w = pack2(P[n][18], P[n][19]);
            dst[3 ^ sw] = o;
        }
    }
    __syncthreads();

    // per-thread read swizzle for A-frags: row low bits = col16
    const int rd_sw = (quad ^ ((col16 >> 1) & 3)) * 4;

    // ---- Phase 2: MLP1 MFMA (per wave: 2 N-tiles over 8 groups) ----
    U4 w2f[8];
    float b2v;
    {
        int cg[8];
        #pragma unroll
        for (int g = 0; g < 8; ++g) cg[g] = s_cntg[g];
        float hs0[8], hs1[8];
        #pragma unroll
        for (int g = 0; g < 8; ++g) { hs0[g] = 0.f; hs1[g] = 0.f; }
        #pragma unroll
        for (int g = 0; g < 8; ++g) {
            const int mts = (cg[g] + 15) >> 4;
            for (int mt = 0; mt < mts; ++mt) {
                U4 au;
                au.u = *(const uint4*)&relb_w[((g<<6) + mt*16 + col16)*16 + rd_sw];
                f32x4 a0 = {0.f,0.f,0.f,0.f}, a1 = {0.f,0.f,0.f,0.f};
                a0 = __builtin_amdgcn_mfma_f32_16x16x32_bf16(au.b, bu0.b, a0, 0,0,0);
                a1 = __builtin_amdgcn_mfma_f32_16x16x32_bf16(au.b, bu1.b, a1, 0,0,0);
                #pragma unroll
                for (int i = 0; i < 4; ++i) {
                    hs0[g] += fmaxf(a0[i] + b10, 0.f);
                    hs1[g] += fmaxf(a1[i] + b11, 0.f);
                }
            }
        }
        // issue first half of W2 (hides under the reduction below)
        float w2rA[32];
        #pragma unroll
        for (int kc = 0; kc < 4; ++kc)
            #pragma unroll
            for (int j = 0; j < 8; ++j)
                w2rA[kc*8+j] = W2[(size_t)(kc*32 + quad*8 + j)*128 + wv*16 + col16];
        b2v = b2[wv*16 + col16];
        // zero pad rows each contributed relu(b1); subtract post-hoc
        const float rb0 = fmaxf(b10, 0.f), rb1 = fmaxf(b11, 0.f);
        #pragma unroll
        for (int g = 0; g < 8; ++g) {
            const int mts = (cg[g] + 15) >> 4;
            const float pad = (float)(mts*16 - cg[g]);
            float v0 = hs0[g], v1 = hs1[g];
            v0 += __shfl_xor(v0, 16); v0 += __shfl_xor(v0, 32);
            v1 += __shfl_xor(v1, 16); v1 += __shfl_xor(v1, 32);
            if (quad == 0) {
                s_h[g*264 + (wv*2+0)*16 + col16] =
                    (unsigned short)f2bf(v0 - pad*rb0);
                s_h[g*264 + (wv*2+1)*16 + col16] =
                    (unsigned short)f2bf(v1 - pad*rb1);
            }
        }
        // pack half A (dies), then load+pack half B
        #pragma unroll
        for (int kc = 0; kc < 4; ++kc) {
            U4 o;
            o.u.x = pack2(w2rA[kc*8+0], w2rA[kc*8+1]);
            o.u.y = pack2(w2rA[kc*8+2], w2rA[kc*8+3]);
            o.u.z = pack2(w2rA[kc*8+4], w2rA[kc*8+5]);
            o.u.w = pack2(w2rA[kc*8+6], w2rA[kc*8+7]);
            w2f[kc] = o;
        }
        float w2rB[32];
        #pragma unroll
        for (int kc = 0; kc < 4; ++kc)
            #pragma unroll
            for (int j = 0; j < 8; ++j)
                w2rB[kc*8+j] = W2[(size_t)((kc+4)*32 + quad*8 + j)*128 + wv*16 + col16];
        #pragma unroll
        for (int kc = 0; kc < 4; ++kc) {
            U4 o;
            o.u.x = pack2(w2rB[kc*8+0], w2rB[kc*8+1]);
            o.u.y = pack2(w2rB[kc*8+2], w2rB[kc*8+3]);
            o.u.z = pack2(w2rB[kc*8+4], w2rB[kc*8+5]);
            o.u.w = pack2(w2rB[kc*8+6], w2rB[kc*8+7]);
            w2f[4+kc] = o;
        }
    }
    __syncthreads();

    // ---- Phase 3: obj_data q[0..12] + W2 GEMM -> q[13..140] ----
    U4 w3f0[5];
    float b3p0, w4p0[3];
    if (t < 104) {
        const int m = t/13, c = t - m*13, n = nb + m;
        float v;
        if (c == 0) v = P[n][24];
        else if (c == 1) v = P[n][25];
        else if (c == 2) v = P[n][7];
        else v = P[n][10 + c - 3];
        s_q[m*168 + c] = (unsigned short)f2bf(v);
    }
    {
        // issue W3 ntl0 raw loads first: hidden under the 8 MFMAs below
        float w3r0[40];
        {
            const int col = wv*16 + col16;
            b3p0 = b3[col];
            w4p0[0] = W4[col*3+0]; w4p0[1] = W4[col*3+1]; w4p0[2] = W4[col*3+2];
            #pragma unroll
            for (int kc = 0; kc < 5; ++kc)
                #pragma unroll
                for (int j = 0; j < 8; ++j) {
                    const int k = kc*32 + quad*8 + j;
                    w3r0[kc*8+j] = (k < 141) ? W3[(size_t)k*256 + col] : 0.f;
                }
        }
        // GEMM in two af-halves (16 live A-regs instead of 32)
        f32x4 acc = {0.f,0.f,0.f,0.f};
        #pragma unroll
        for (int half = 0; half < 2; ++half) {
            U4 af[4];
            #pragma unroll
            for (int kc = 0; kc < 4; ++kc)
                af[kc].u = *(const uint4*)&s_h[(lane & 15)*264 + (half*4+kc)*32 + quad*8];
            #pragma unroll
            for (int kc = 0; kc < 4; ++kc)
                acc = __builtin_amdgcn_mfma_f32_16x16x32_bf16(
                    af[kc].b, w2f[half*4+kc].b, acc, 0,0,0);
        }
        #pragma unroll
        for (int i = 0; i < 4; ++i) {
            const int row = quad*4 + i;
            const float cnt = (float)s_cntg[row & 7];
            s_q[row*168 + 13 + wv*16 + col16] =
                (unsigned short)f2bf(acc[i] + cnt*b2v);
        }
        // pack ntl0
        #pragma unroll
        for (int kc = 0; kc < 5; ++kc) {
            U4 o;
            o.u.x = pack2(w3r0[kc*8+0], w3r0[kc*8+1]);
            o.u.y = pack2(w3r0[kc*8+2], w3r0[kc*8+3]);
            o.u.z = pack2(w3r0[kc*8+4], w3r0[kc*8+5]);
            o.u.w = pack2(w3r0[kc*8+6], w3r0[kc*8+7]);
            w3f0[kc] = o;
        }
    }
    __syncthreads();

    // ---- Phase 4: W3 GEMM + relu + W4 partials (ntl1 loads pipelined) ----
    {
        U4 af3[5];
        #pragma unroll
        for (int kc = 0; kc < 5; ++kc)
            af3[kc].u = *(const uint4*)&s_q[(lane & 15)*168 + kc*32 + quad*8];
        // issue ntl1 raw loads; wait covered by ntl0 GEMM below
        float w3r1[40], b3p1, w4p1[3];
        {
            const int col = (wv + 8)*16 + col16;
            b3p1 = b3[col];
            w4p1[0] = W4[col*3+0]; w4p1[1] = W4[col*3+1]; w4p1[2] = W4[col*3+2];
            #pragma unroll
            for (int kc = 0; kc < 5; ++kc)
                #pragma unroll
                for (int j = 0; j < 8; ++j) {
                    const int k = kc*32 + quad*8 + j;
                    w3r1[kc*8+j] = (k < 141) ? W3[(size_t)k*256 + col] : 0.f;
                }
        }
        float p[4][3];
        #pragma unroll
        for (int i = 0; i < 4; ++i) { p[i][0]=0.f; p[i][1]=0.f; p[i][2]=0.f; }
        // ntl0 compute
        {
            f32x4 acc = {0.f,0.f,0.f,0.f};
            #pragma unroll
            for (int kc = 0; kc < 5; ++kc)
                acc = __builtin_amdgcn_mfma_f32_16x16x32_bf16(
                    af3[kc].b, w3f0[kc].b, acc, 0,0,0);
            #pragma unroll
            for (int i = 0; i < 4; ++i) {
                const float h = fmaxf(acc[i] + b3p0, 0.f);
                p[i][0] = fmaf(h, w4p0[0], p[i][0]);
                p[i][1] = fmaf(h, w4p0[1], p[i][1]);
                p[i][2] = fmaf(h, w4p0[2], p[i][2]);
            }
        }
        // pack + compute ntl1
        {
            U4 w3f1[5];
            #pragma unroll
            for (int kc = 0; kc < 5; ++kc) {
                U4 o;
                o.u.x = pack2(w3r1[kc*8+0], w3r1[kc*8+1]);
                o.u.y = pack2(w3r1[kc*8+2], w3r1[kc*8+3]);
                o.u.z = pack2(w3r1[kc*8+4], w3r1[kc*8+5]);
                o.u.w = pack2(w3r1[kc*8+6], w3r1[kc*8+7]);
                w3f1[kc] = o;
            }
            f32x4 acc = {0.f,0.f,0.f,0.f};
            #pragma unroll
            for (int kc = 0; kc < 5; ++kc)
                acc = __builtin_amdgcn_mfma_f32_16x16x32_bf16(
                    af3[kc].b, w3f1[kc].b, acc, 0,0,0);
            #pragma unroll
            for (int i = 0; i < 4; ++i) {
                const float h = fmaxf(acc[i] + b3p1, 0.f);
                p[i][0] = fmaf(h, w4p1[0], p[i][0]);
                p[i][1] = fmaf(h, w4p1[1], p[i][1]);
                p[i][2] = fmaf(h, w4p1[2], p[i][2]);
            }
        }
        #pragma unroll
        for (int off = 1; off < 16; off <<= 1)
            #pragma unroll
            for (int i = 0; i < 4; ++i) {
                p[i][0] += __shfl_xor(p[i][0], off);
                p[i][1] += __shfl_xor(p[i][1], off);
                p[i][2] += __shfl_xor(p[i][2], off);
            }
        if (col16 == 0)
            #pragma unroll
            for (int i = 0; i < 4; ++i) {
                s_red[wv][quad*4+i][0] = p[i][0];
                s_red[wv][quad*4+i][1] = p[i][1];
                s_red[wv][quad*4+i][2] = p[i][2];
            }
    }
    __syncthreads();
    if (t < 48) {
        const int m = t/3, o = t - m*3;
        float acc = e_b4;   // b4[o] prefetched (o == t%3)
        #pragma unroll
        for (int w = 0; w < 8; ++w) acc += s_red[w][m][o];
        s_outv[m][o] = acc;
    }
    __syncthreads();

    // ---- Phase 5: epilogue (all scalars prefetched in phase 0) ----
    if (t < 48) {
        const int m = t/6, i = t - m*6, n = nb + m;
        if (n >= 1) {
            const float q0 = s_outv[m][0]*e_vs0 + e_vm0;
            const float q1 = s_outv[m][1]*e_vs1 + e_vm1;
            const float q2 = s_outv[m][2]*e_vs2 + e_vm2;
            const float cr = P[n][22], sr = P[n][23];
            const float xd0 = cr*q0 - sr*q1;
            const float xd1 = sr*q0 + cr*q1;
            const int im = i % 3;
            const float xd = (im == 0) ? xd0 : (im == 1) ? xd1 : q2;
            float base = 0.f;
            if (i == 0) base = P[n][0];
            else if (i == 1) base = P[n][1];
            else if (i == 2) base = P[n][26];
            out[((size_t)b*NM1 + (n-1))*6 + i] = base + xd;
        }
    }
}

extern "C" void kernel_launch(void* const* d_in, const int* in_sizes, int n_in,
                              void* d_out, int out_size, void* d_ws, size_t ws_size,
                              hipStream_t stream) {
    const float* objects_state = (const float*)d_in[0];
    const float* objects_shape = (const float*)d_in[1];
    const float* relation_info = (const float*)d_in[2];
    const float* s_mean  = (const float*)d_in[3];
    const float* s_std   = (const float*)d_in[4];
    const float* sh_mean = (const float*)d_in[5];
    const float* sh_std  = (const float*)d_in[6];
    const float* v_mean  = (const float*)d_in[7];
    const float* v_std   = (const float*)d_in[8];
    const float* W1 = (const float*)d_in[9];
    const float* b1 = (const float*)d_in[10];
    const float* W2 = (const float*)d_in[11];
    const float* b2 = (const float*)d_in[12];
    const float* W3 = (const float*)d_in[13];
    const float* b3 = (const float*)d_in[14];
    const float* W4 = (const float*)d_in[15];
    const float* b4 = (const float*)d_in[16];
    (void)d_ws; (void)ws_size; (void)in_sizes; (void)n_in; (void)out_size;

    fused_kernel<<<dim3(BB*8), dim3(512), 0, stream>>>(
        objects_state, objects_shape, relation_info,
        s_mean, s_std, sh_mean, sh_std, v_mean, v_std,
        W1, b1, W2, b2, W3, b3, W4, b4,
        (float*)d_out);
}

// Round 5
// 104.818 us; speedup vs baseline: 1.3135x; 1.1804x over previous
//
#include <hip/hip_runtime.h>
#include <math.h>

#define BB 64
#define NN 64
#define NM1 63
#define RR (NN*(NN-1))

// workspace layout (bytes)
#define WS1_OFF 0              // W1c B-frags: 16 tiles * 64 * 16B = 16 KB
#define WS2_OFF 16384          // W2 B-frags: 8 nt * 8 kc * 64 * 16B = 64 KB
#define WS3_OFF 81920          // W3 B-frags: 16 nt * 5 kc * 64 * 16B = 80 KB
#define WSO_OFF 163840         // per-object prep: 4096 obj * 28 f32 = 459 KB

typedef short bf16x8 __attribute__((ext_vector_type(8)));
typedef float f32x4 __attribute__((ext_vector_type(4)));
union U4 { uint4 u; bf16x8 b; };

__device__ inline unsigned int f2bf(float f) {
    unsigned int u = __float_as_uint(f);
    return (u + 0x7FFFu + ((u >> 16) & 1u)) >> 16;   // RNE fp32->bf16
}
__device__ inline unsigned int pack2(float a, float b) {
    return f2bf(a) | (f2bf(b) << 16);
}

// ============ prep: weight pack (blocks 0..39) + object precompute (40..55) =
// Per-object record (28 f32): [0]=st0 [1]=st1 [2..9]=nst [10..19]=nsh
// [20]=cos(nst2) [21]=sin(nst2) [22]=cos(st2) [23]=sin(st2)
// [24]=vrot0 [25]=vrot1 [26]=st2raw [27]=pad
__global__ __launch_bounds__(256) void prep_kernel(
    const float* __restrict__ objects_state,
    const float* __restrict__ objects_shape,
    const float* __restrict__ s_mean, const float* __restrict__ s_std,
    const float* __restrict__ sh_mean, const float* __restrict__ sh_std,
    const float* __restrict__ W1, const float* __restrict__ W2,
    const float* __restrict__ W3, unsigned char* __restrict__ ws)
{
    const int t = threadIdx.x;
    if (blockIdx.x < 40) {
        const int u = blockIdx.x*4 + (t >> 6), l = t & 63;
        const int col16 = l & 15, quad = l >> 4;
        float v[8];
        uint4* dst;
        if (u < 16) {
            // W1 compact rows: kc<12 -> orig kc; 12..21 -> orig kc+10 (sender
            // shape); 22..31 -> orig kc-10 (receiver shape)
            const int nt = u, col = nt*16 + col16;
            #pragma unroll
            for (int j = 0; j < 8; ++j) {
                const int k = quad*8 + j;
                const int orig = k < 12 ? k : (k < 22 ? k+10 : k-10);
                v[j] = W1[orig*256 + col];
            }
            dst = (uint4*)(ws + WS1_OFF) + (nt*64 + l);
        } else if (u < 80) {
            const int w = u-16, nt = w >> 3, kc = w & 7, col = nt*16 + col16;
            #pragma unroll
            for (int j = 0; j < 8; ++j)
                v[j] = W2[(size_t)(kc*32 + quad*8 + j)*128 + col];
            dst = (uint4*)(ws + WS2_OFF) + ((nt*8 + kc)*64 + l);
        } else {
            const int w = u-80, nt = w/5, kc = w - nt*5, col = nt*16 + col16;
            #pragma unroll
            for (int j = 0; j < 8; ++j) {
                const int k = kc*32 + quad*8 + j;
                v[j] = (k < 141) ? W3[(size_t)k*256 + col] : 0.f;  // zero K-pad
            }
            dst = (uint4*)(ws + WS3_OFF) + ((nt*5 + kc)*64 + l);
        }
        uint4 o;
        o.x = pack2(v[0], v[1]); o.y = pack2(v[2], v[3]);
        o.z = pack2(v[4], v[5]); o.w = pack2(v[6], v[7]);
        *dst = o;
    } else {
        const int obj = (blockIdx.x - 40)*256 + t;
        float st[8], sh[10];
        #pragma unroll
        for (int c = 0; c < 8; ++c)  st[c] = objects_state[(size_t)obj*8 + c];
        #pragma unroll
        for (int c = 0; c < 10; ++c) sh[c] = objects_shape[(size_t)obj*10 + c];
        float f[28];
        f[0] = st[0]; f[1] = st[1]; f[26] = st[2]; f[27] = 0.f;
        #pragma unroll
        for (int c = 0; c < 8; ++c)  f[2+c]  = (st[c] - s_mean[c]) / s_std[c];
        #pragma unroll
        for (int c = 0; c < 10; ++c) f[10+c] = (sh[c] - sh_mean[c]) / sh_std[c];
        const float sa = sinf(f[4]), ca = cosf(f[4]);
        const float sr = sinf(st[2]), cr = cosf(st[2]);
        f[20] = ca; f[21] = sa; f[22] = cr; f[23] = sr;
        f[24] =  ca*f[5] + sa*f[6];
        f[25] = -sa*f[5] + ca*f[6];
        float4* dst = (float4*)(ws + WSO_OFF + (size_t)obj*112);
        #pragma unroll
        for (int q = 0; q < 7; ++q)
            dst[q] = make_float4(f[q*4], f[q*4+1], f[q*4+2], f[q*4+3]);
    }
}

// ============ main: G=8 receivers/block, 512 threads, grid B*8 ============
// Streams pre-packed bf16 weights from ws (transient regs, no staging ->
// spill-free at the compiler's 64-VGPR target; rounds 2-4 proved in-register
// f32->bf16 packing spills 46-82MB to scratch).
// LDS conflict fixes vs round-0: relb_w 16B-chunk XOR swizzle
// (A-frag reads were 8-way: 596K->285K measured), P stride 29 (phase-1
// P[j] reads were 8-way; 29 coprime with 32 banks).
__global__ __launch_bounds__(512) void main_kernel(
    const float* __restrict__ relation_info,
    const float* __restrict__ v_mean, const float* __restrict__ v_std,
    const float* __restrict__ b1, const float* __restrict__ b2,
    const float* __restrict__ b3,
    const float* __restrict__ W4, const float* __restrict__ b4,
    const unsigned char* __restrict__ ws,
    float* __restrict__ out)
{
    __shared__ __align__(16) float P[64][29];                 // 7424 B
    __shared__ __align__(16) unsigned int relb_w[8*64*16];    // 32768 B (row=64B)
    __shared__ __align__(16) float RI[1512];                  // 6048 B
    __shared__ __align__(16) unsigned short s_h[16*264];      // 8448 B
    __shared__ __align__(16) unsigned short s_q[16*168];      // 5376 B
    __shared__ int   s_cntg[8];
    __shared__ float s_red[8][16][3];
    __shared__ float s_outv[16][3];

    const int b  = blockIdx.x >> 3;
    const int nb = (blockIdx.x & 7) * 8;
    const int t  = threadIdx.x;
    const int wv = t >> 6, lane = t & 63, col16 = lane & 15, quad = lane >> 4;

    // ---- epilogue scalar prefetch (cuts 2 L2 round-trips off block tail;
    // 7 regs, t<48 only) ----
    float e_vs0=0.f,e_vs1=0.f,e_vs2=0.f,e_vm0=0.f,e_vm1=0.f,e_vm2=0.f,e_b4=0.f;
    if (t < 48) {
        e_vs0 = v_std[0]; e_vs1 = v_std[1]; e_vs2 = v_std[2];
        e_vm0 = v_mean[0]; e_vm1 = v_mean[1]; e_vm2 = v_mean[2];
        e_b4  = b4[t % 3];
    }

    // ---- Phase 0: stage ----
    {
        uint4 z = make_uint4(0,0,0,0);
        uint4* relb4 = (uint4*)relb_w;
        #pragma unroll
        for (int r = 0; r < 4; ++r) relb4[r*512 + t] = z;
        if (t < 336) ((uint4*)s_q)[t] = z;
        if (t < 8) s_cntg[t] = 0;
        // P copy: ws records are 28-f32 packed; LDS rows are stride-29.
        // 448 float4 loads, scalar stores (one-time).
        if (t < 448) {
            const int obj = t / 7, q = t - obj*7;
            const float4 v = *(const float4*)(ws + WSO_OFF
                                + (size_t)(b*64 + obj)*112 + q*16);
            P[obj][q*4+0] = v.x; P[obj][q*4+1] = v.y;
            P[obj][q*4+2] = v.z; P[obj][q*4+3] = v.w;
        }
        const float* rsrc = relation_info + ((size_t)b*RR + nb*NM1)*3;
        #pragma unroll
        for (int r = 0; r < 3; ++r) {
            const int idx = r*512 + t;
            if (idx < 1512) RI[idx] = rsrc[idx];
        }
    }
    __syncthreads();

    // ---- Phase 1: build relation rows (1 candidate/thread) ----
    // relb_w row = 64B = 4x16B chunks; chunk' = chunk ^ ((row>>1)&3)
    if (t < 504) {
        const int g = t/63, k = t - g*63, n = nb + g, j = k + (k >= n);
        const float dx = P[n][0] - P[j][0];
        const float dy = P[n][1] - P[j][1];
        const float dist = sqrtf(dx*dx + dy*dy);
        if (dist < 0.35f && dist != 0.0f) {
            const int slot = atomicAdd(&s_cntg[g], 1);
            const int row = (g << 6) + slot;
            const int sw = (row >> 1) & 3;
            float f[32];
            f[0] = RI[t*3]; f[1] = RI[t*3+1]; f[2] = RI[t*3+2];
            const float rd0 = P[n][2], rd1 = P[n][3], rd2 = P[n][4],
                        rd3 = P[n][5], rd4 = P[n][6], rd5 = P[n][7];
            const float ca = P[n][20], sa = P[n][21];
            const float d0 = P[j][2]-rd0, d1 = P[j][3]-rd1, d2 = P[j][4]-rd2,
                        d3 = P[j][5]-rd3, d4 = P[j][6]-rd4, d5 = P[j][7]-rd5;
            f[3]  =  ca*d0 + sa*d1;
            f[4]  = -sa*d0 + ca*d1;
            f[5]  =  ca*d3 + sa*d4;
            f[6]  = -sa*d3 + ca*d4;
            f[7]  =  ca*P[j][8] + sa*P[j][9];
            f[8]  = -sa*P[j][8] + ca*P[j][9];
            f[9]  = sinf(2.f*d2);
            f[10] = cosf(2.f*d2);
            f[11] = d5;
            #pragma unroll
            for (int c = 0; c < 10; ++c) f[12+c] = P[j][10+c];   // sender shape
            #pragma unroll
            for (int c = 0; c < 10; ++c) f[22+c] = P[n][10+c];   // receiver shape
            uint4* dst = (uint4*)&relb_w[row*16];
            #pragma unroll
            for (int w4 = 0; w4 < 4; ++w4) {
                uint4 o;
                o.x = pack2(f[w4*8+0], f[w4*8+1]);
                o.y = pack2(f[w4*8+2], f[w4*8+3]);
                o.z = pack2(f[w4*8+4], f[w4*8+5]);
                o.w = pack2(f[w4*8+6], f[w4*8+7]);
                dst[w4 ^ sw] = o;
            }
        }
    }
    __syncthreads();

    // per-thread read swizzle for A-frags: (row>>1)&3 == (col16>>1)&3 since
    // row = 16*m + col16 with m*16 aligned
    const int rd_sw = (quad ^ ((col16 >> 1) & 3)) * 4;

    // ---- Phase 2: MLP1 MFMA (per wave: 2 N-tiles over 8 groups) ----
    {
        int cg[8];
        #pragma unroll
        for (int g = 0; g < 8; ++g) cg[g] = s_cntg[g];
        const uint4* w1f = (const uint4*)(ws + WS1_OFF);
        U4 bu0, bu1;
        bu0.u = w1f[(wv*2+0)*64 + lane];
        bu1.u = w1f[(wv*2+1)*64 + lane];
        const float b10 = b1[(wv*2+0)*16 + col16];
        const float b11 = b1[(wv*2+1)*16 + col16];
        float hs0[8], hs1[8];
        #pragma unroll
        for (int g = 0; g < 8; ++g) { hs0[g] = 0.f; hs1[g] = 0.f; }
        #pragma unroll
        for (int g = 0; g < 8; ++g) {
            const int mts = (cg[g] + 15) >> 4;
            for (int mt = 0; mt < mts; ++mt) {
                U4 au;
                au.u = *(const uint4*)&relb_w[((g<<6) + mt*16 + col16)*16 + rd_sw];
                f32x4 a0 = {0.f,0.f,0.f,0.f}, a1 = {0.f,0.f,0.f,0.f};
                a0 = __builtin_amdgcn_mfma_f32_16x16x32_bf16(au.b, bu0.b, a0, 0,0,0);
                a1 = __builtin_amdgcn_mfma_f32_16x16x32_bf16(au.b, bu1.b, a1, 0,0,0);
                #pragma unroll
                for (int i = 0; i < 4; ++i) {
                    hs0[g] += fmaxf(a0[i] + b10, 0.f);
                    hs1[g] += fmaxf(a1[i] + b11, 0.f);
                }
            }
        }
        // zero pad rows each contributed relu(b1); subtract them post-hoc
        const float rb0 = fmaxf(b10, 0.f), rb1 = fmaxf(b11, 0.f);
        #pragma unroll
        for (int g = 0; g < 8; ++g) {
            const int mts = (cg[g] + 15) >> 4;
            const float pad = (float)(mts*16 - cg[g]);
            float v0 = hs0[g], v1 = hs1[g];
            v0 += __shfl_xor(v0, 16); v0 += __shfl_xor(v0, 32);
            v1 += __shfl_xor(v1, 16); v1 += __shfl_xor(v1, 32);
            if (quad == 0) {
                s_h[g*264 + (wv*2+0)*16 + col16] =
                    (unsigned short)f2bf(v0 - pad*rb0);
                s_h[g*264 + (wv*2+1)*16 + col16] =
                    (unsigned short)f2bf(v1 - pad*rb1);
            }
        }
    }
    __syncthreads();

    // ---- Phase 3: obj_data q[0..12] + W2 GEMM -> q[13..140] ----
    if (t < 104) {
        const int m = t/13, c = t - m*13, n = nb + m;
        float v;
        if (c == 0) v = P[n][24];
        else if (c == 1) v = P[n][25];
        else if (c == 2) v = P[n][7];
        else v = P[n][10 + c - 3];
        s_q[m*168 + c] = (unsigned short)f2bf(v);
    }
    {
        U4 af[8];
        #pragma unroll
        for (int kc = 0; kc < 8; ++kc)
            af[kc].u = *(const uint4*)&s_h[(lane & 15)*264 + kc*32 + quad*8];
        float cntv[4];
        #pragma unroll
        for (int i = 0; i < 4; ++i)
            cntv[i] = (float)s_cntg[(quad*4 + i) & 7];
        const uint4* w2f = (const uint4*)(ws + WS2_OFF);
        f32x4 acc = {0.f,0.f,0.f,0.f};
        #pragma unroll
        for (int kc = 0; kc < 8; ++kc) {
            U4 bu; bu.u = w2f[(wv*8 + kc)*64 + lane];
            acc = __builtin_amdgcn_mfma_f32_16x16x32_bf16(af[kc].b, bu.b, acc, 0,0,0);
        }
        const float b2v = b2[wv*16 + col16];
        #pragma unroll
        for (int i = 0; i < 4; ++i) {
            const int row = quad*4 + i;
            s_q[row*168 + 13 + wv*16 + col16] =
                (unsigned short)f2bf(acc[i] + cntv[i]*b2v);
        }
    }
    __syncthreads();

    // ---- Phase 4: W3 GEMM + relu + W4 partials ----
    {
        U4 af3[5];
        #pragma unroll
        for (int kc = 0; kc < 5; ++kc)
            af3[kc].u = *(const uint4*)&s_q[(lane & 15)*168 + kc*32 + quad*8];
        const uint4* w3f = (const uint4*)(ws + WS3_OFF);
        float p[4][3];
        #pragma unroll
        for (int i = 0; i < 4; ++i) { p[i][0]=0.f; p[i][1]=0.f; p[i][2]=0.f; }
        #pragma unroll
        for (int ntl = 0; ntl < 2; ++ntl) {
            const int nt = wv + ntl*8, col = nt*16 + col16;
            f32x4 acc = {0.f,0.f,0.f,0.f};
            #pragma unroll
            for (int kc = 0; kc < 5; ++kc) {
                U4 bu; bu.u = w3f[(nt*5 + kc)*64 + lane];
                acc = __builtin_amdgcn_mfma_f32_16x16x32_bf16(af3[kc].b, bu.b, acc, 0,0,0);
            }
            const float b3v = b3[col];
            const float w40 = W4[col*3+0], w41 = W4[col*3+1], w42 = W4[col*3+2];
            #pragma unroll
            for (int i = 0; i < 4; ++i) {
                const float h = fmaxf(acc[i] + b3v, 0.f);
                p[i][0] = fmaf(h, w40, p[i][0]);
                p[i][1] = fmaf(h, w41, p[i][1]);
                p[i][2] = fmaf(h, w42, p[i][2]);
            }
        }
        #pragma unroll
        for (int off = 1; off < 16; off <<= 1)
            #pragma unroll
            for (int i = 0; i < 4; ++i) {
                p[i][0] += __shfl_xor(p[i][0], off);
                p[i][1] += __shfl_xor(p[i][1], off);
                p[i][2] += __shfl_xor(p[i][2], off);
            }
        if (col16 == 0)
            #pragma unroll
            for (int i = 0; i < 4; ++i) {
                s_red[wv][quad*4+i][0] = p[i][0];
                s_red[wv][quad*4+i][1] = p[i][1];
                s_red[wv][quad*4+i][2] = p[i][2];
            }
    }
    __syncthreads();
    if (t < 48) {
        const int m = t/3, o = t - m*3;
        float acc = e_b4;   // b4[o] prefetched (o == t%3)
        #pragma unroll
        for (int w = 0; w < 8; ++w) acc += s_red[w][m][o];
        s_outv[m][o] = acc;
    }
    __syncthreads();

    // ---- Phase 5: epilogue (scalars prefetched at kernel top) ----
    if (t < 48) {
        const int m = t/6, i = t - m*6, n = nb + m;
        if (n >= 1) {
            const float q0 = s_outv[m][0]*e_vs0 + e_vm0;
            const float q1 = s_outv[m][1]*e_vs1 + e_vm1;
            const float q2 = s_outv[m][2]*e_vs2 + e_vm2;
            const float cr = P[n][22], sr = P[n][23];
            const float xd0 = cr*q0 - sr*q1;
            const float xd1 = sr*q0 + cr*q1;
            const int im = i % 3;
            const float xd = (im == 0) ? xd0 : (im == 1) ? xd1 : q2;
            float base = 0.f;
            if (i == 0) base = P[n][0];
            else if (i == 1) base = P[n][1];
            else if (i == 2) base = P[n][26];
            out[((size_t)b*NM1 + (n-1))*6 + i] = base + xd;
        }
    }
}

extern "C" void kernel_launch(void* const* d_in, const int* in_sizes, int n_in,
                              void* d_out, int out_size, void* d_ws, size_t ws_size,
                              hipStream_t stream) {
    const float* objects_state = (const float*)d_in[0];
    const float* objects_shape = (const float*)d_in[1];
    const float* relation_info = (const float*)d_in[2];
    const float* s_mean  = (const float*)d_in[3];
    const float* s_std   = (const float*)d_in[4];
    const float* sh_mean = (const float*)d_in[5];
    const float* sh_std  = (const float*)d_in[6];
    const float* v_mean  = (const float*)d_in[7];
    const float* v_std   = (const float*)d_in[8];
    const float* W1 = (const float*)d_in[9];
    const float* b1 = (const float*)d_in[10];
    const float* W2 = (const float*)d_in[11];
    const float* b2 = (const float*)d_in[12];
    const float* W3 = (const float*)d_in[13];
    const float* b3 = (const float*)d_in[14];
    const float* W4 = (const float*)d_in[15];
    const float* b4 = (const float*)d_in[16];
    unsigned char* ws = (unsigned char*)d_ws;

    prep_kernel<<<dim3(56), dim3(256), 0, stream>>>(
        objects_state, objects_shape, s_mean, s_std, sh_mean, sh_std,
        W1, W2, W3, ws);
    main_kernel<<<dim3(BB*8), dim3(512), 0, stream>>>(
        relation_info, v_mean, v_std, b1, b2, b3, W4, b4,
        ws, (float*)d_out);
}

// Round 6
// 104.143 us; speedup vs baseline: 1.3220x; 1.0065x over previous
//
#include <hip/hip_runtime.h>
#include <math.h>

#define BB 64
#define NN 64
#define NM1 63
#define RR (NN*(NN-1))

// workspace layout (bytes)
#define WS1_OFF 0              // W1c B-frags: 16 tiles * 64 * 16B = 16 KB
#define WS2_OFF 16384          // W2 B-frags: 8 nt * 8 kc * 64 * 16B = 64 KB
#define WS3_OFF 81920          // W3 B-frags: 16 nt * 5 kc * 64 * 16B = 80 KB

typedef short bf16x8 __attribute__((ext_vector_type(8)));
typedef float f32x4 __attribute__((ext_vector_type(4)));
union U4 { uint4 u; bf16x8 b; };

__device__ inline unsigned int f2bf(float f) {
    unsigned int u = __float_as_uint(f);
    return (u + 0x7FFFu + ((u >> 16) & 1u)) >> 16;   // RNE fp32->bf16
}
__device__ inline unsigned int pack2(float a, float b) {
    return f2bf(a) | (f2bf(b) << 16);
}

// ============ prep: weight pack only (40 blocks) ============
// Object precompute moved into main (round-1-proven spill-safe) -> no WSO
// round-trip, 16 fewer blocks.
__global__ __launch_bounds__(256) void prep_kernel(
    const float* __restrict__ W1, const float* __restrict__ W2,
    const float* __restrict__ W3, unsigned char* __restrict__ ws)
{
    const int t = threadIdx.x;
    const int u = blockIdx.x*4 + (t >> 6), l = t & 63;
    const int col16 = l & 15, quad = l >> 4;
    float v[8];
    uint4* dst;
    if (u < 16) {
        // W1 compact rows: kc<12 -> orig kc; 12..21 -> orig kc+10 (sender
        // shape); 22..31 -> orig kc-10 (receiver shape)
        const int nt = u, col = nt*16 + col16;
        #pragma unroll
        for (int j = 0; j < 8; ++j) {
            const int k = quad*8 + j;
            const int orig = k < 12 ? k : (k < 22 ? k+10 : k-10);
            v[j] = W1[orig*256 + col];
        }
        dst = (uint4*)(ws + WS1_OFF) + (nt*64 + l);
    } else if (u < 80) {
        const int w = u-16, nt = w >> 3, kc = w & 7, col = nt*16 + col16;
        #pragma unroll
        for (int j = 0; j < 8; ++j)
            v[j] = W2[(size_t)(kc*32 + quad*8 + j)*128 + col];
        dst = (uint4*)(ws + WS2_OFF) + ((nt*8 + kc)*64 + l);
    } else {
        const int w = u-80, nt = w/5, kc = w - nt*5, col = nt*16 + col16;
        #pragma unroll
        for (int j = 0; j < 8; ++j) {
            const int k = kc*32 + quad*8 + j;
            v[j] = (k < 141) ? W3[(size_t)k*256 + col] : 0.f;  // zero K-pad
        }
        dst = (uint4*)(ws + WS3_OFF) + ((nt*5 + kc)*64 + l);
    }
    uint4 o;
    o.x = pack2(v[0], v[1]); o.y = pack2(v[2], v[3]);
    o.z = pack2(v[4], v[5]); o.w = pack2(v[6], v[7]);
    *dst = o;
}

// ============ main: G=8 receivers/block, 512 threads, grid B*8 ============
// Streams pre-packed bf16 weights from ws (transient regs, no staging ->
// spill-free at the compiler's 64-VGPR target; rounds 2-4 proved in-register
// f32->bf16 packing spills 46-82MB to scratch).
// vs round-5: wave==group phase 1 with ballot slots (no LDS atomics,
// P[n] reads wave-broadcast), P computed in-block (no WSO round-trip),
// W1 frags + RI hoisted to kernel top (latency hidden under phase 0/1).
__global__ __launch_bounds__(512) void main_kernel(
    const float* __restrict__ objects_state,
    const float* __restrict__ objects_shape,
    const float* __restrict__ relation_info,
    const float* __restrict__ s_mean, const float* __restrict__ s_std,
    const float* __restrict__ sh_mean, const float* __restrict__ sh_std,
    const float* __restrict__ v_mean, const float* __restrict__ v_std,
    const float* __restrict__ b1, const float* __restrict__ b2,
    const float* __restrict__ b3,
    const float* __restrict__ W4, const float* __restrict__ b4,
    const unsigned char* __restrict__ ws,
    float* __restrict__ out)
{
    __shared__ __align__(16) float P[64][29];                 // 7424 B (29: bank-coprime)
    __shared__ __align__(16) unsigned int relb_w[8*64*16];    // 32768 B (row=64B)
    __shared__ __align__(16) unsigned short s_h[16*264];      // 8448 B
    __shared__ __align__(16) unsigned short s_q[16*168];      // 5376 B
    __shared__ int   s_cntg[8];
    __shared__ float s_red[8][16][3];
    __shared__ float s_outv[16][3];

    const int b  = blockIdx.x >> 3;
    const int nb = (blockIdx.x & 7) * 8;
    const int t  = threadIdx.x;
    const int wv = t >> 6, lane = t & 63, col16 = lane & 15, quad = lane >> 4;

    // ---- W1 B-frags + b1: hoisted to top (prep finished via stream order;
    // latency hides under phase 0/1). Same regs as loading in phase 2. ----
    U4 bu0, bu1;
    {
        const uint4* w1f = (const uint4*)(ws + WS1_OFF);
        bu0.u = w1f[(wv*2+0)*64 + lane];
        bu1.u = w1f[(wv*2+1)*64 + lane];
    }
    const float b10 = b1[(wv*2+0)*16 + col16];
    const float b11 = b1[(wv*2+1)*16 + col16];

    // ---- relation_info direct read (wave wv owns group wv, lane = cand) ----
    float ri0 = 0.f, ri1 = 0.f, ri2 = 0.f;
    if (lane < 63) {
        const float* rp = relation_info
            + ((size_t)b*RR + (size_t)(nb + wv)*NM1 + lane)*3;
        ri0 = rp[0]; ri1 = rp[1]; ri2 = rp[2];
    }

    // ---- epilogue scalar prefetch (t<48 only; 7 regs) ----
    float e_vs0=0.f,e_vs1=0.f,e_vs2=0.f,e_vm0=0.f,e_vm1=0.f,e_vm2=0.f,e_b4=0.f;
    if (t < 48) {
        e_vs0 = v_std[0]; e_vs1 = v_std[1]; e_vs2 = v_std[2];
        e_vm0 = v_mean[0]; e_vm1 = v_mean[1]; e_vm2 = v_mean[2];
        e_b4  = b4[t % 3];
    }

    // ---- Phase 0: zero-init + per-object record compute ----
    // Per-object record: [0]=st0 [1]=st1 [2..9]=nst [10..19]=nsh
    // [20]=cos(nst2) [21]=sin(nst2) [22]=cos(st2) [23]=sin(st2)
    // [24]=vrot0 [25]=vrot1 [26]=st2raw [27..28]=pad
    {
        uint4 z = make_uint4(0,0,0,0);
        uint4* relb4 = (uint4*)relb_w;
        #pragma unroll
        for (int r = 0; r < 4; ++r) relb4[r*512 + t] = z;
        if (t < 336) ((uint4*)s_q)[t] = z;
        if (t < 64) {
            const int n = b*64 + t;
            const float4* sp4 = (const float4*)(objects_state + (size_t)n*8);
            const float4 sA = sp4[0], sB = sp4[1];
            float st[8] = {sA.x, sA.y, sA.z, sA.w, sB.x, sB.y, sB.z, sB.w};
            const float2* hp2 = (const float2*)(objects_shape + (size_t)n*10);
            float sh[10];
            #pragma unroll
            for (int c = 0; c < 5; ++c) {
                const float2 v = hp2[c];
                sh[c*2] = v.x; sh[c*2+1] = v.y;
            }
            float f[28];
            f[0] = st[0]; f[1] = st[1]; f[26] = st[2]; f[27] = 0.f;
            #pragma unroll
            for (int c = 0; c < 8; ++c)  f[2+c]  = (st[c] - s_mean[c]) / s_std[c];
            #pragma unroll
            for (int c = 0; c < 10; ++c) f[10+c] = (sh[c] - sh_mean[c]) / sh_std[c];
            // libm sinf/cosf to match reference precision
            const float sa = sinf(f[4]), ca = cosf(f[4]);
            const float sr = sinf(st[2]), cr = cosf(st[2]);
            f[20] = ca; f[21] = sa; f[22] = cr; f[23] = sr;
            f[24] =  ca*f[5] + sa*f[6];
            f[25] = -sa*f[5] + ca*f[6];
            #pragma unroll
            for (int c = 0; c < 28; ++c) P[t][c] = f[c];
        }
    }
    __syncthreads();

    // ---- Phase 1: build relation rows. wave wv == group, lane == candidate.
    // Slots via ballot prefix (no LDS atomics); P[n] reads are broadcast.
    // relb_w row = 64B = 4x16B chunks; chunk' = chunk ^ ((row>>1)&3).
    {
        const int g = wv, n = nb + g;
        bool pred = false;
        int j = 0;
        if (lane < 63) {
            j = lane + (lane >= n);
            const float dx = P[n][0] - P[j][0];
            const float dy = P[n][1] - P[j][1];
            const float dist = sqrtf(dx*dx + dy*dy);
            pred = (dist < 0.35f) && (dist != 0.0f);
        }
        const unsigned long long mask = __ballot(pred);
        if (lane == 0) s_cntg[g] = __popcll(mask);
        if (pred) {
            const int slot = __popcll(mask & ((1ull << lane) - 1ull));
            const int row = (g << 6) + slot;
            const int sw = (row >> 1) & 3;
            float f[32];
            f[0] = ri0; f[1] = ri1; f[2] = ri2;
            const float ca = P[n][20], sa = P[n][21];
            const float d0 = P[j][2]-P[n][2], d1 = P[j][3]-P[n][3];
            const float d2 = P[j][4]-P[n][4], d3 = P[j][5]-P[n][5];
            const float d4 = P[j][6]-P[n][6], d5 = P[j][7]-P[n][7];
            f[3]  =  ca*d0 + sa*d1;
            f[4]  = -sa*d0 + ca*d1;
            f[5]  =  ca*d3 + sa*d4;
            f[6]  = -sa*d3 + ca*d4;
            f[7]  =  ca*P[j][8] + sa*P[j][9];
            f[8]  = -sa*P[j][8] + ca*P[j][9];
            f[9]  = sinf(2.f*d2);
            f[10] = cosf(2.f*d2);
            f[11] = d5;
            #pragma unroll
            for (int c = 0; c < 10; ++c) f[12+c] = P[j][10+c];   // sender shape
            #pragma unroll
            for (int c = 0; c < 10; ++c) f[22+c] = P[n][10+c];   // receiver shape
            uint4* dst = (uint4*)&relb_w[row*16];
            #pragma unroll
            for (int w4 = 0; w4 < 4; ++w4) {
                uint4 o;
                o.x = pack2(f[w4*8+0], f[w4*8+1]);
                o.y = pack2(f[w4*8+2], f[w4*8+3]);
                o.z = pack2(f[w4*8+4], f[w4*8+5]);
                o.w = pack2(f[w4*8+6], f[w4*8+7]);
                dst[w4 ^ sw] = o;
            }
        }
    }
    __syncthreads();

    // per-thread read swizzle for A-frags: (row>>1)&3 == (col16>>1)&3 since
    // row = 16*m + col16 with m*16 aligned
    const int rd_sw = (quad ^ ((col16 >> 1) & 3)) * 4;

    // ---- Phase 2: MLP1 MFMA (per wave: 2 N-tiles over 8 groups) ----
    {
        int cg[8];
        #pragma unroll
        for (int g = 0; g < 8; ++g) cg[g] = s_cntg[g];
        float hs0[8], hs1[8];
        #pragma unroll
        for (int g = 0; g < 8; ++g) { hs0[g] = 0.f; hs1[g] = 0.f; }
        #pragma unroll
        for (int g = 0; g < 8; ++g) {
            const int mts = (cg[g] + 15) >> 4;
            for (int mt = 0; mt < mts; ++mt) {
                U4 au;
                au.u = *(const uint4*)&relb_w[((g<<6) + mt*16 + col16)*16 + rd_sw];
                f32x4 a0 = {0.f,0.f,0.f,0.f}, a1 = {0.f,0.f,0.f,0.f};
                a0 = __builtin_amdgcn_mfma_f32_16x16x32_bf16(au.b, bu0.b, a0, 0,0,0);
                a1 = __builtin_amdgcn_mfma_f32_16x16x32_bf16(au.b, bu1.b, a1, 0,0,0);
                #pragma unroll
                for (int i = 0; i < 4; ++i) {
                    hs0[g] += fmaxf(a0[i] + b10, 0.f);
                    hs1[g] += fmaxf(a1[i] + b11, 0.f);
                }
            }
        }
        // zero pad rows each contributed relu(b1); subtract them post-hoc
        const float rb0 = fmaxf(b10, 0.f), rb1 = fmaxf(b11, 0.f);
        #pragma unroll
        for (int g = 0; g < 8; ++g) {
            const int mts = (cg[g] + 15) >> 4;
            const float pad = (float)(mts*16 - cg[g]);
            float v0 = hs0[g], v1 = hs1[g];
            v0 += __shfl_xor(v0, 16); v0 += __shfl_xor(v0, 32);
            v1 += __shfl_xor(v1, 16); v1 += __shfl_xor(v1, 32);
            if (quad == 0) {
                s_h[g*264 + (wv*2+0)*16 + col16] =
                    (unsigned short)f2bf(v0 - pad*rb0);
                s_h[g*264 + (wv*2+1)*16 + col16] =
                    (unsigned short)f2bf(v1 - pad*rb1);
            }
        }
    }
    __syncthreads();

    // ---- Phase 3: obj_data q[0..12] + W2 GEMM -> q[13..140] ----
    if (t < 104) {
        const int m = t/13, c = t - m*13, n = nb + m;
        float v;
        if (c == 0) v = P[n][24];
        else if (c == 1) v = P[n][25];
        else if (c == 2) v = P[n][7];
        else v = P[n][10 + c - 3];
        s_q[m*168 + c] = (unsigned short)f2bf(v);
    }
    {
        U4 af[8];
        #pragma unroll
        for (int kc = 0; kc < 8; ++kc)
            af[kc].u = *(const uint4*)&s_h[(lane & 15)*264 + kc*32 + quad*8];
        float cntv[4];
        #pragma unroll
        for (int i = 0; i < 4; ++i)
            cntv[i] = (float)s_cntg[(quad*4 + i) & 7];
        const uint4* w2f = (const uint4*)(ws + WS2_OFF);
        f32x4 acc = {0.f,0.f,0.f,0.f};
        #pragma unroll
        for (int kc = 0; kc < 8; ++kc) {
            U4 bu; bu.u = w2f[(wv*8 + kc)*64 + lane];
            acc = __builtin_amdgcn_mfma_f32_16x16x32_bf16(af[kc].b, bu.b, acc, 0,0,0);
        }
        const float b2v = b2[wv*16 + col16];
        #pragma unroll
        for (int i = 0; i < 4; ++i) {
            const int row = quad*4 + i;
            s_q[row*168 + 13 + wv*16 + col16] =
                (unsigned short)f2bf(acc[i] + cntv[i]*b2v);
        }
    }
    __syncthreads();

    // ---- Phase 4: W3 GEMM + relu + W4 partials ----
    {
        U4 af3[5];
        #pragma unroll
        for (int kc = 0; kc < 5; ++kc)
            af3[kc].u = *(const uint4*)&s_q[(lane & 15)*168 + kc*32 + quad*8];
        const uint4* w3f = (const uint4*)(ws + WS3_OFF);
        float p[4][3];
        #pragma unroll
        for (int i = 0; i < 4; ++i) { p[i][0]=0.f; p[i][1]=0.f; p[i][2]=0.f; }
        #pragma unroll
        for (int ntl = 0; ntl < 2; ++ntl) {
            const int nt = wv + ntl*8, col = nt*16 + col16;
            f32x4 acc = {0.f,0.f,0.f,0.f};
            #pragma unroll
            for (int kc = 0; kc < 5; ++kc) {
                U4 bu; bu.u = w3f[(nt*5 + kc)*64 + lane];
                acc = __builtin_amdgcn_mfma_f32_16x16x32_bf16(af3[kc].b, bu.b, acc, 0,0,0);
            }
            const float b3v = b3[col];
            const float w40 = W4[col*3+0], w41 = W4[col*3+1], w42 = W4[col*3+2];
            #pragma unroll
            for (int i = 0; i < 4; ++i) {
                const float h = fmaxf(acc[i] + b3v, 0.f);
                p[i][0] = fmaf(h, w40, p[i][0]);
                p[i][1] = fmaf(h, w41, p[i][1]);
                p[i][2] = fmaf(h, w42, p[i][2]);
            }
        }
        #pragma unroll
        for (int off = 1; off < 16; off <<= 1)
            #pragma unroll
            for (int i = 0; i < 4; ++i) {
                p[i][0] += __shfl_xor(p[i][0], off);
                p[i][1] += __shfl_xor(p[i][1], off);
                p[i][2] += __shfl_xor(p[i][2], off);
            }
        if (col16 == 0)
            #pragma unroll
            for (int i = 0; i < 4; ++i) {
                s_red[wv][quad*4+i][0] = p[i][0];
                s_red[wv][quad*4+i][1] = p[i][1];
                s_red[wv][quad*4+i][2] = p[i][2];
            }
    }
    __syncthreads();
    if (t < 48) {
        const int m = t/3, o = t - m*3;
        float acc = e_b4;   // b4[o] prefetched (o == t%3)
        #pragma unroll
        for (int w = 0; w < 8; ++w) acc += s_red[w][m][o];
        s_outv[m][o] = acc;
    }
    __syncthreads();

    // ---- Phase 5: epilogue (scalars prefetched at kernel top) ----
    if (t < 48) {
        const int m = t/6, i = t - m*6, n = nb + m;
        if (n >= 1) {
            const float q0 = s_outv[m][0]*e_vs0 + e_vm0;
            const float q1 = s_outv[m][1]*e_vs1 + e_vm1;
            const float q2 = s_outv[m][2]*e_vs2 + e_vm2;
            const float cr = P[n][22], sr = P[n][23];
            const float xd0 = cr*q0 - sr*q1;
            const float xd1 = sr*q0 + cr*q1;
            const int im = i % 3;
            const float xd = (im == 0) ? xd0 : (im == 1) ? xd1 : q2;
            float base = 0.f;
            if (i == 0) base = P[n][0];
            else if (i == 1) base = P[n][1];
            else if (i == 2) base = P[n][26];
            out[((size_t)b*NM1 + (n-1))*6 + i] = base + xd;
        }
    }
}

extern "C" void kernel_launch(void* const* d_in, const int* in_sizes, int n_in,
                              void* d_out, int out_size, void* d_ws, size_t ws_size,
                              hipStream_t stream) {
    const float* objects_state = (const float*)d_in[0];
    const float* objects_shape = (const float*)d_in[1];
    const float* relation_info = (const float*)d_in[2];
    const float* s_mean  = (const float*)d_in[3];
    const float* s_std   = (const float*)d_in[4];
    const float* sh_mean = (const float*)d_in[5];
    const float* sh_std  = (const float*)d_in[6];
    const float* v_mean  = (const float*)d_in[7];
    const float* v_std   = (const float*)d_in[8];
    const float* W1 = (const float*)d_in[9];
    const float* b1 = (const float*)d_in[10];
    const float* W2 = (const float*)d_in[11];
    const float* b2 = (const float*)d_in[12];
    const float* W3 = (const float*)d_in[13];
    const float* b3 = (const float*)d_in[14];
    const float* W4 = (const float*)d_in[15];
    const float* b4 = (const float*)d_in[16];
    unsigned char* ws = (unsigned char*)d_ws;

    prep_kernel<<<dim3(40), dim3(256), 0, stream>>>(W1, W2, W3, ws);
    main_kernel<<<dim3(BB*8), dim3(512), 0, stream>>>(
        objects_state, objects_shape, relation_info,
        s_mean, s_std, sh_mean, sh_std, v_mean, v_std,
        b1, b2, b3, W4, b4, ws, (float*)d_out);
}